// Round 12
// baseline (78.995 us; speedup 1.0000x reference)
//
#include <hip/hip_runtime.h>
#include <stdint.h>

#define NBINS 4096        // coarse histogram bins (key >> 20)
#define NB2   2048        // refine sub-bins
#define NBLK  2048        // filter blocks = private slot regions
#define SLOT  16          // candidate slots per block (expected ~2 hits)
#define OVF_CAP 8192
#define CAND2_CAP 8192    // global mirror capacity
#define LDS_CAND2 1024    // LDS rank capacity (expected M2 ~ 70-150)
#define SAMP_PTS 131072   // contiguous prefix sample for the threshold
#define SBLK 128          // sample blocks (256 thr x 4 pts = 1024 pts/block)
#define CHUNK_PTS 256     // points per wave-chunk
#define CHUNK_F4  192     // float4 per wave-chunk (256*3/4 = 3 KB)

// Distance key: f32 bit pattern of sqrt((dx*dx + dy*dy) + dz*dz), computed with
// explicit round-to-nearest intrinsics so hipcc cannot FMA-contract and diverge
// from the numpy reference. Non-negative floats are order-isomorphic to their
// uint32 bit patterns.
__device__ __forceinline__ uint32_t dist_key(float x, float y, float z,
                                             float px, float py, float pz) {
    float dx = __fsub_rn(x, px);
    float dy = __fsub_rn(y, py);
    float dz = __fsub_rn(z, pz);
    float s = __fadd_rn(__fadd_rn(__fmul_rn(dx, dx), __fmul_rn(dy, dy)),
                        __fmul_rn(dz, dz));
    float d = __fsqrt_rn(s);
    return __float_as_uint(d);
}

// ---------------------------------------------------------------------------
// Fused sample-histogram + scan, fence-free handoff (proven rounds 9/11).
// Samples are a subset of the full set => cut with sampled-cum >= K has
// full-cum >= K: exact-safe.
// ---------------------------------------------------------------------------
__global__ void __launch_bounds__(256) sample_scan_kernel(
        const float* __restrict__ pts, const float* __restrict__ P1,
        uint32_t* __restrict__ ghist, uint32_t* __restrict__ cutp,
        uint32_t* __restrict__ done_s, int nsamp, int K) {
    __shared__ uint32_t lh[NBINS];
    __shared__ uint32_t ssum[256];
    __shared__ int is_last;
    for (int i = threadIdx.x; i < NBINS; i += 256) lh[i] = 0;
    __syncthreads();
    float px = P1[0], py = P1[1], pz = P1[2];
    int gid = blockIdx.x * 256 + threadIdx.x;
    const float4* p4 = (const float4*)pts;
    if (gid * 4 < nsamp) {
        float4 A = p4[gid * 3 + 0];
        float4 Bv = p4[gid * 3 + 1];
        float4 Cv = p4[gid * 3 + 2];
        atomicAdd(&lh[dist_key(A.x, A.y, A.z, px, py, pz) >> 20], 1u);
        atomicAdd(&lh[dist_key(A.w, Bv.x, Bv.y, px, py, pz) >> 20], 1u);
        atomicAdd(&lh[dist_key(Bv.z, Bv.w, Cv.x, px, py, pz) >> 20], 1u);
        atomicAdd(&lh[dist_key(Cv.y, Cv.z, Cv.w, px, py, pz) >> 20], 1u);
    }
    __syncthreads();
    for (int i = threadIdx.x; i < NBINS; i += 256) {
        uint32_t v = lh[i];
        if (v) atomicAdd(&ghist[i], v);
    }
    __syncthreads();
    if (threadIdx.x == 0) {
        asm volatile("s_waitcnt vmcnt(0)" ::: "memory");
        uint32_t old = __hip_atomic_fetch_add(done_s, 1u, __ATOMIC_RELAXED,
                                              __HIP_MEMORY_SCOPE_AGENT);
        is_last = (old == (uint32_t)(gridDim.x - 1));
    }
    __syncthreads();
    if (!is_last) return;

    int t = threadIdx.x;
    uint32_t mine[16];
    uint32_t local = 0;
    for (int j = 0; j < 16; ++j) {
        mine[j] = __hip_atomic_load(&ghist[t * 16 + j], __ATOMIC_RELAXED,
                                    __HIP_MEMORY_SCOPE_AGENT);
        local += mine[j];
    }
    ssum[t] = local;
    __syncthreads();
    for (int off = 1; off < 256; off <<= 1) {
        uint32_t v = (t >= off) ? ssum[t - off] : 0;
        __syncthreads();
        ssum[t] += v;
        __syncthreads();
    }
    uint32_t incl = ssum[t];
    uint32_t excl = incl - local;
    if (excl < (uint32_t)K && incl >= (uint32_t)K) {
        uint32_t run = excl;
        for (int j = 0; j < 16; ++j) {
            run += mine[j];
            if (run >= (uint32_t)K) { *cutp = (uint32_t)(t * 16 + j); break; }
        }
    }
}

// ---------------------------------------------------------------------------
// Fused filter + refine-select with FENCE-FREE handoff (r8 structure, r9
// coherence mechanism). Filter = proven r6 core: coalesced copy-pattern loads,
// conflict-free LDS park transpose, zero global atomics on the common path.
// Cross-block handoff: gslots/gcount/ovf are written with atomicExch (RMWs
// complete at the coherence point — a handful per block, NO threadfence / L2
// writeback, unlike r8's 2048 fences), then per-block vmcnt(0) drain +
// RELAXED done-counter RMW. The last block reads everything back with relaxed
// agent-scope atomic loads (bypass stale local caches; pattern proven by the
// r9/r11 sample_scan handoff) and runs refine + exact rank-select in-dispatch,
// with refine LDS overlaid on the park buffer (17.4 KB, 8 blocks/CU kept).
// ---------------------------------------------------------------------------
__global__ void __launch_bounds__(256) filter_refine_kernel(
        const float* __restrict__ pts, const float* __restrict__ P1,
        const uint32_t* __restrict__ cutp,
        unsigned long long* __restrict__ gslots,
        uint32_t* __restrict__ gcount,
        uint32_t* __restrict__ ovf_cnt, unsigned long long* __restrict__ ovf,
        uint32_t* __restrict__ done_f,
        unsigned long long* __restrict__ cand2,
        float* __restrict__ out,
        int nchunks, int N, int K) {
    __shared__ __align__(16) unsigned char smem[17472];
    __shared__ unsigned long long lhits[SLOT];
    __shared__ uint32_t lcnt;
    __shared__ int is_last;
    __shared__ uint32_t cut2_s, m2_s;
    float4 (*park)[CHUNK_F4] = (float4 (*)[CHUNK_F4])smem;

    if (threadIdx.x == 0) lcnt = 0;
    __syncthreads();

    const float4* p4 = (const float4*)pts;
    float px = P1[0], py = P1[1], pz = P1[2];
    uint32_t cb = *cutp;
    int w = threadIdx.x >> 6;
    int lane = threadIdx.x & 63;
    int b = blockIdx.x;
    int cpb = (nchunks + NBLK - 1) / NBLK;
    int cbeg = b * cpb;
    int cend = cbeg + cpb; if (cend > nchunks) cend = nchunks;

    float4 r0, r1, r2;
    int c = cbeg + w;
    if (c < cend) {
        const float4* s = p4 + (size_t)c * CHUNK_F4;
        r0 = s[lane]; r1 = s[lane + 64]; r2 = s[lane + 128];
    }
    for (; c < cend; c += 4) {
        park[w][lane] = r0;
        park[w][lane + 64] = r1;
        park[w][lane + 128] = r2;
        int cn = c + 4;
        if (cn < cend) {   // prefetch next chunk; latency hides under compute
            const float4* s = p4 + (size_t)cn * CHUNK_F4;
            r0 = s[lane]; r1 = s[lane + 64]; r2 = s[lane + 128];
        }
        asm volatile("s_waitcnt lgkmcnt(0)" ::: "memory");
        const float* fb = (const float*)&park[w][0] + lane * 12;
        float4 A  = *(const float4*)(fb);
        float4 Bv = *(const float4*)(fb + 4);
        float4 Cv = *(const float4*)(fb + 8);
        uint32_t kk[4];
        kk[0] = dist_key(A.x, A.y, A.z, px, py, pz);
        kk[1] = dist_key(A.w, Bv.x, Bv.y, px, py, pz);
        kk[2] = dist_key(Bv.z, Bv.w, Cv.x, px, py, pz);
        kk[3] = dist_key(Cv.y, Cv.z, Cv.w, px, py, pz);
        uint32_t pbase = (uint32_t)c * CHUNK_PTS + (uint32_t)lane * 4;
        #pragma unroll
        for (int j = 0; j < 4; ++j) {
            if ((kk[j] >> 20) <= cb) {
                unsigned long long cv = ((unsigned long long)kk[j] << 32) |
                                        (unsigned long long)(pbase + j);
                uint32_t pos = atomicAdd(&lcnt, 1u);
                if (pos < SLOT) lhits[pos] = cv;
                else {
                    uint32_t op = atomicAdd(ovf_cnt, 1u);
                    if (op < OVF_CAP) atomicExch(&ovf[op], cv);
                }
            }
        }
    }
    // tail (N not a multiple of CHUNK_PTS): last-indexed block, thread 0
    if (b == NBLK - 1 && threadIdx.x == 0) {
        for (int i = nchunks * CHUNK_PTS; i < N; ++i) {
            uint32_t kk = dist_key(pts[3 * i], pts[3 * i + 1], pts[3 * i + 2], px, py, pz);
            if ((kk >> 20) <= cb) {
                unsigned long long cv = ((unsigned long long)kk << 32) |
                                        (unsigned long long)(uint32_t)i;
                uint32_t pos = atomicAdd(&lcnt, 1u);
                if (pos < SLOT) lhits[pos] = cv;
                else {
                    uint32_t op = atomicAdd(ovf_cnt, 1u);
                    if (op < OVF_CAP) atomicExch(&ovf[op], cv);
                }
            }
        }
    }
    __syncthreads();
    uint32_t n = lcnt; if (n > SLOT) n = SLOT;
    // coherence-point RMW writes (visible device-wide once vmcnt-retired)
    if (threadIdx.x < n) atomicExch(&gslots[(size_t)b * SLOT + threadIdx.x],
                                    lhits[threadIdx.x]);
    if (threadIdx.x == 0) atomicExch(&gcount[b], n);
    __syncthreads();
    if (threadIdx.x == 0) {
        asm volatile("s_waitcnt vmcnt(0)" ::: "memory");
        uint32_t old = __hip_atomic_fetch_add(done_f, 1u, __ATOMIC_RELAXED,
                                              __HIP_MEMORY_SCOPE_AGENT);
        is_last = (old == (uint32_t)(gridDim.x - 1));
    }
    __syncthreads();
    if (!is_last) return;

    // ---- refine + exact select (256 threads, LDS overlaid on park) ----
    uint32_t* hist2 = (uint32_t*)smem;                            // 2048 (8 KB)
    uint32_t* ssum  = (uint32_t*)(smem + 8192);                   // 256 (1 KB)
    unsigned long long* lc = (unsigned long long*)(smem + 9216);  // 1024 (8 KB)
    int t = threadIdx.x;
    unsigned long long R = ((unsigned long long)(cb + 1)) << 20;
    uint32_t M32 = (uint32_t)((((unsigned long long)NB2) << 32) / R);
    uint32_t novf = __hip_atomic_load(ovf_cnt, __ATOMIC_RELAXED,
                                      __HIP_MEMORY_SCOPE_AGENT);
    if (novf > OVF_CAP) novf = OVF_CAP;

    for (int i = t; i < NB2; i += 256) hist2[i] = 0;
    if (t == 0) { m2_s = 0; cut2_s = NB2 - 1; }
    __syncthreads();
    for (int bb = t; bb < NBLK; bb += 256) {
        uint32_t nn = __hip_atomic_load(&gcount[bb], __ATOMIC_RELAXED,
                                        __HIP_MEMORY_SCOPE_AGENT);
        if (nn > SLOT) nn = SLOT;
        for (uint32_t j = 0; j < nn; ++j) {
            unsigned long long cv = __hip_atomic_load(
                &gslots[(size_t)bb * SLOT + j], __ATOMIC_RELAXED,
                __HIP_MEMORY_SCOPE_AGENT);
            uint32_t key = (uint32_t)(cv >> 32);
            atomicAdd(&hist2[(uint32_t)(((unsigned long long)key * M32) >> 32)], 1u);
        }
    }
    for (uint32_t i = t; i < novf; i += 256) {
        unsigned long long cv = __hip_atomic_load(&ovf[i], __ATOMIC_RELAXED,
                                                  __HIP_MEMORY_SCOPE_AGENT);
        uint32_t key = (uint32_t)(cv >> 32);
        atomicAdd(&hist2[(uint32_t)(((unsigned long long)key * M32) >> 32)], 1u);
    }
    __syncthreads();

    uint32_t mine[8];
    uint32_t local = 0;
    for (int j = 0; j < 8; ++j) { mine[j] = hist2[t * 8 + j]; local += mine[j]; }
    ssum[t] = local;
    __syncthreads();
    for (int off = 1; off < 256; off <<= 1) {
        uint32_t v = (t >= off) ? ssum[t - off] : 0;
        __syncthreads();
        ssum[t] += v;
        __syncthreads();
    }
    uint32_t incl = ssum[t], excl = incl - local;
    if (excl < (uint32_t)K && incl >= (uint32_t)K) {
        uint32_t run = excl;
        for (int j = 0; j < 8; ++j) {
            run += mine[j];
            if (run >= (uint32_t)K) { cut2_s = (uint32_t)(t * 8 + j); break; }
        }
    }
    __syncthreads();
    uint32_t c2 = cut2_s;

    for (int bb = t; bb < NBLK; bb += 256) {
        uint32_t nn = __hip_atomic_load(&gcount[bb], __ATOMIC_RELAXED,
                                        __HIP_MEMORY_SCOPE_AGENT);
        if (nn > SLOT) nn = SLOT;
        for (uint32_t j = 0; j < nn; ++j) {
            unsigned long long cv = __hip_atomic_load(
                &gslots[(size_t)bb * SLOT + j], __ATOMIC_RELAXED,
                __HIP_MEMORY_SCOPE_AGENT);
            uint32_t key = (uint32_t)(cv >> 32);
            if ((uint32_t)(((unsigned long long)key * M32) >> 32) <= c2) {
                uint32_t pos = atomicAdd(&m2_s, 1u);
                if (pos < LDS_CAND2) lc[pos] = cv;
                if (pos < CAND2_CAP) cand2[pos] = cv;
            }
        }
    }
    for (uint32_t i = t; i < novf; i += 256) {
        unsigned long long cv = __hip_atomic_load(&ovf[i], __ATOMIC_RELAXED,
                                                  __HIP_MEMORY_SCOPE_AGENT);
        uint32_t key = (uint32_t)(cv >> 32);
        if ((uint32_t)(((unsigned long long)key * M32) >> 32) <= c2) {
            uint32_t pos = atomicAdd(&m2_s, 1u);
            if (pos < LDS_CAND2) lc[pos] = cv;
            if (pos < CAND2_CAP) cand2[pos] = cv;
        }
    }
    __syncthreads();
    uint32_t M2 = m2_s;

    if (M2 <= LDS_CAND2) {
        for (uint32_t i = t; i < M2; i += 256) {
            unsigned long long ci = lc[i];
            uint32_t rank = 0;
            for (uint32_t j = 0; j < M2; ++j) rank += (lc[j] < ci) ? 1u : 0u;
            if (rank < (uint32_t)K) {
                uint32_t idx = (uint32_t)(ci & 0xFFFFFFFFu);
                out[3 * rank + 0] = pts[3 * idx + 0];
                out[3 * rank + 1] = pts[3 * idx + 1];
                out[3 * rank + 2] = pts[3 * idx + 2];
                out[3 * K + rank] = (float)idx;  // indices exact (< 2^23)
            }
        }
    } else {
        if (M2 > CAND2_CAP) M2 = CAND2_CAP;
        for (uint32_t i = t; i < M2; i += 256) {
            unsigned long long ci = cand2[i];
            uint32_t rank = 0;
            for (uint32_t j = 0; j < M2; ++j) rank += (cand2[j] < ci) ? 1u : 0u;
            if (rank < (uint32_t)K) {
                uint32_t idx = (uint32_t)(ci & 0xFFFFFFFFu);
                out[3 * rank + 0] = pts[3 * idx + 0];
                out[3 * rank + 1] = pts[3 * idx + 1];
                out[3 * rank + 2] = pts[3 * idx + 2];
                out[3 * K + rank] = (float)idx;
            }
        }
    }
}

extern "C" void kernel_launch(void* const* d_in, const int* in_sizes, int n_in,
                              void* d_out, int out_size, void* d_ws, size_t ws_size,
                              hipStream_t stream) {
    const float* pts = (const float*)d_in[0];
    const float* P1  = (const float*)d_in[1];
    float* out = (float*)d_out;

    int N = in_sizes[0] / 3;
    int nchunks = N / CHUNK_PTS;
    int K = out_size / 4;  // out = K*3 coords + K indices
    int nsamp = (N < SAMP_PTS) ? (N / 4) * 4 : SAMP_PTS;

    uint32_t* w       = (uint32_t*)d_ws;
    uint32_t* ovf_cnt = w + 0;
    uint32_t* cutp    = w + 1;
    uint32_t* done_s  = w + 2;
    uint32_t* done_f  = w + 3;
    uint32_t* hist    = w + 4;                          // NBINS
    uint32_t* gcount  = w + 4 + NBINS;                  // NBLK
    unsigned long long* gslots = (unsigned long long*)(w + 4 + NBINS + NBLK); // NBLK*SLOT
    unsigned long long* ovf    = gslots + (size_t)NBLK * SLOT;                // OVF_CAP
    unsigned long long* cand2  = ovf + OVF_CAP;                               // CAND2_CAP

    // zero: ovf_cnt, cut, done_s, done_f, hist
    // (gcount/gslots/cand2 written before read every call)
    hipMemsetAsync(w, 0, (size_t)(4 + NBINS) * sizeof(uint32_t), stream);
    sample_scan_kernel<<<SBLK, 256, 0, stream>>>(pts, P1, hist, cutp, done_s, nsamp, K);
    filter_refine_kernel<<<NBLK, 256, 0, stream>>>(pts, P1, cutp, gslots, gcount,
                                                   ovf_cnt, ovf, done_f, cand2,
                                                   out, nchunks, N, K);
}

// Round 13
// 46.450 us; speedup vs baseline: 1.7007x; 1.7007x over previous
//
#include <hip/hip_runtime.h>
#include <stdint.h>

#define NBINS 4096
#define NB2   4096
#define NBLK  2048        // filter blocks = private slot regions
#define SLOT  16          // candidate slots per block (expected ~2 hits)
#define OVF_CAP 8192
#define LDS_CAND 8192
#define SAMP_PTS 131072   // contiguous prefix sample for the threshold
#define SBLK 128          // sample blocks (256 thr x 4 pts = 1024 pts/block)
#define TILE_PTS 1024     // points per block-tile in the filter
#define TILE_F4  768      // float4 per tile

// Distance key: f32 bit pattern of sqrt((dx*dx + dy*dy) + dz*dz), computed with
// explicit round-to-nearest intrinsics so hipcc cannot FMA-contract and diverge
// from the numpy reference. Non-negative floats are order-isomorphic to their
// uint32 bit patterns.
__device__ __forceinline__ uint32_t dist_key(float x, float y, float z,
                                             float px, float py, float pz) {
    float dx = __fsub_rn(x, px);
    float dy = __fsub_rn(y, py);
    float dz = __fsub_rn(z, pz);
    float s = __fadd_rn(__fadd_rn(__fmul_rn(dx, dx), __fmul_rn(dy, dy)),
                        __fmul_rn(dz, dz));
    float d = __fsqrt_rn(s);
    return __float_as_uint(d);
}

// ---------------------------------------------------------------------------
// Fused sample-histogram + scan, fence-free handoff (proven rounds 7/9/11).
// Samples are a subset of the full set => cut with sampled-cum >= K has
// full-cum >= K: exact-safe.
// ---------------------------------------------------------------------------
__global__ void __launch_bounds__(256) sample_scan_kernel(
        const float* __restrict__ pts, const float* __restrict__ P1,
        uint32_t* __restrict__ ghist, uint32_t* __restrict__ cutp,
        uint32_t* __restrict__ done_s, int nsamp, int K) {
    __shared__ uint32_t lh[NBINS];
    __shared__ uint32_t ssum[256];
    __shared__ int is_last;
    for (int i = threadIdx.x; i < NBINS; i += 256) lh[i] = 0;
    __syncthreads();
    float px = P1[0], py = P1[1], pz = P1[2];
    int gid = blockIdx.x * 256 + threadIdx.x;
    const float4* p4 = (const float4*)pts;
    if (gid * 4 < nsamp) {
        float4 A = p4[gid * 3 + 0];
        float4 Bv = p4[gid * 3 + 1];
        float4 Cv = p4[gid * 3 + 2];
        atomicAdd(&lh[dist_key(A.x, A.y, A.z, px, py, pz) >> 20], 1u);
        atomicAdd(&lh[dist_key(A.w, Bv.x, Bv.y, px, py, pz) >> 20], 1u);
        atomicAdd(&lh[dist_key(Bv.z, Bv.w, Cv.x, px, py, pz) >> 20], 1u);
        atomicAdd(&lh[dist_key(Cv.y, Cv.z, Cv.w, px, py, pz) >> 20], 1u);
    }
    __syncthreads();
    for (int i = threadIdx.x; i < NBINS; i += 256) {
        uint32_t v = lh[i];
        if (v) atomicAdd(&ghist[i], v);
    }
    __syncthreads();
    if (threadIdx.x == 0) {
        asm volatile("s_waitcnt vmcnt(0)" ::: "memory");
        uint32_t old = __hip_atomic_fetch_add(done_s, 1u, __ATOMIC_RELAXED,
                                              __HIP_MEMORY_SCOPE_AGENT);
        is_last = (old == (uint32_t)(gridDim.x - 1));
    }
    __syncthreads();
    if (!is_last) return;

    int t = threadIdx.x;
    uint32_t mine[16];
    uint32_t local = 0;
    for (int j = 0; j < 16; ++j) {
        mine[j] = __hip_atomic_load(&ghist[t * 16 + j], __ATOMIC_RELAXED,
                                    __HIP_MEMORY_SCOPE_AGENT);
        local += mine[j];
    }
    ssum[t] = local;
    __syncthreads();
    for (int off = 1; off < 256; off <<= 1) {
        uint32_t v = (t >= off) ? ssum[t - off] : 0;
        __syncthreads();
        ssum[t] += v;
        __syncthreads();
    }
    uint32_t incl = ssum[t];
    uint32_t excl = incl - local;
    if (excl < (uint32_t)K && incl >= (uint32_t)K) {
        uint32_t run = excl;
        for (int j = 0; j < 16; ++j) {
            run += mine[j];
            if (run >= (uint32_t)K) { *cutp = (uint32_t)(t * 16 + j); break; }
        }
    }
}

// ---------------------------------------------------------------------------
// Full pass, DIRECT register reads, zero LDS staging. Thread t of each tile
// loads the 3 consecutive float4s of its point-quad (48 B). Per wave
// instruction the 64 lanes span 3 KB (48 lines); the quad's 3 instructions
// reuse exactly those lines, so every line is fetched once. No LDS park, no
// lgkmcnt chain, no per-tile wait: pure m13-style TLP scheduling at max
// occupancy. Hits (rare) buffer in LDS, flush once to this block's PRIVATE
// gslots region — zero global atomics on the common path (proven r6).
// ---------------------------------------------------------------------------
__global__ void __launch_bounds__(256) filter_kernel(
        const float* __restrict__ pts, const float* __restrict__ P1,
        const uint32_t* __restrict__ cutp,
        unsigned long long* __restrict__ gslots,
        uint32_t* __restrict__ gcount,
        uint32_t* __restrict__ ovf_cnt, unsigned long long* __restrict__ ovf,
        int ntiles, int N) {
    __shared__ unsigned long long lhits[SLOT];
    __shared__ uint32_t lcnt;
    if (threadIdx.x == 0) lcnt = 0;
    __syncthreads();

    const float4* p4 = (const float4*)pts;
    float px = P1[0], py = P1[1], pz = P1[2];
    uint32_t cb = *cutp;
    int b = blockIdx.x;
    int tpb = (ntiles + NBLK - 1) / NBLK;     // tiles per block
    int tbeg = b * tpb;
    int tend = tbeg + tpb; if (tend > ntiles) tend = ntiles;

    for (int tl = tbeg; tl < tend; ++tl) {
        const float4* s = p4 + (size_t)tl * TILE_F4 + 3 * threadIdx.x;
        float4 A  = s[0];
        float4 Bv = s[1];
        float4 Cv = s[2];
        uint32_t kk[4];
        kk[0] = dist_key(A.x, A.y, A.z, px, py, pz);
        kk[1] = dist_key(A.w, Bv.x, Bv.y, px, py, pz);
        kk[2] = dist_key(Bv.z, Bv.w, Cv.x, px, py, pz);
        kk[3] = dist_key(Cv.y, Cv.z, Cv.w, px, py, pz);
        uint32_t pbase = (uint32_t)tl * TILE_PTS + (uint32_t)threadIdx.x * 4;
        #pragma unroll
        for (int j = 0; j < 4; ++j) {
            if ((kk[j] >> 20) <= cb) {
                unsigned long long cv = ((unsigned long long)kk[j] << 32) |
                                        (unsigned long long)(pbase + j);
                uint32_t pos = atomicAdd(&lcnt, 1u);
                if (pos < SLOT) lhits[pos] = cv;
                else {
                    uint32_t op = atomicAdd(ovf_cnt, 1u);
                    if (op < OVF_CAP) ovf[op] = cv;
                }
            }
        }
    }
    // tail (N not a multiple of TILE_PTS): last block, thread 0
    if (b == NBLK - 1 && threadIdx.x == 0) {
        for (int i = ntiles * TILE_PTS; i < N; ++i) {
            uint32_t kk = dist_key(pts[3 * i], pts[3 * i + 1], pts[3 * i + 2], px, py, pz);
            if ((kk >> 20) <= cb) {
                unsigned long long cv = ((unsigned long long)kk << 32) |
                                        (unsigned long long)(uint32_t)i;
                uint32_t pos = atomicAdd(&lcnt, 1u);
                if (pos < SLOT) lhits[pos] = cv;
                else {
                    uint32_t op = atomicAdd(ovf_cnt, 1u);
                    if (op < OVF_CAP) ovf[op] = cv;
                }
            }
        }
    }
    __syncthreads();
    uint32_t n = lcnt; if (n > SLOT) n = SLOT;
    if (threadIdx.x < n) gslots[(size_t)b * SLOT + threadIdx.x] = lhits[threadIdx.x];
    if (threadIdx.x == 0) gcount[b] = n;
}

// ---------------------------------------------------------------------------
// Single-block refine + exact select (unchanged, proven). NB2-bin LDS
// histogram over [0,(cb+1)<<20) via monotone multiply-shift; scan -> tight
// cut2 (count >= K); compact (M2 ~ 70-100) to LDS + global mirror; exact rank
// by composite (key<<32)|idx — same order + tie-break as top_k(-dist).
// ---------------------------------------------------------------------------
__global__ void __launch_bounds__(1024) refine_select_kernel(
        const uint32_t* __restrict__ gcount,
        const unsigned long long* __restrict__ gslots,
        const uint32_t* __restrict__ ovf_cnt,
        const unsigned long long* __restrict__ ovf,
        const uint32_t* __restrict__ cutp,
        unsigned long long* __restrict__ cand2,
        const float* __restrict__ pts,
        float* __restrict__ out, int K) {
    __shared__ uint32_t hist2[NB2];
    __shared__ uint32_t ssum[1024];
    __shared__ unsigned long long lcand[LDS_CAND];
    __shared__ uint32_t cut2_s, m2_s;
    int t = threadIdx.x;
    uint32_t cb = *cutp;
    unsigned long long R = ((unsigned long long)(cb + 1)) << 20;
    uint32_t M32 = (uint32_t)((((unsigned long long)NB2) << 32) / R);
    uint32_t novf = *ovf_cnt; if (novf > OVF_CAP) novf = OVF_CAP;

    for (int i = t; i < NB2; i += 1024) hist2[i] = 0;
    if (t == 0) { m2_s = 0; cut2_s = NB2 - 1; }
    __syncthreads();
    for (int b = t; b < NBLK; b += 1024) {
        uint32_t n = gcount[b]; if (n > SLOT) n = SLOT;
        for (uint32_t j = 0; j < n; ++j) {
            uint32_t key = (uint32_t)(gslots[(size_t)b * SLOT + j] >> 32);
            atomicAdd(&hist2[(uint32_t)(((unsigned long long)key * M32) >> 32)], 1u);
        }
    }
    for (uint32_t i = t; i < novf; i += 1024) {
        uint32_t key = (uint32_t)(ovf[i] >> 32);
        atomicAdd(&hist2[(uint32_t)(((unsigned long long)key * M32) >> 32)], 1u);
    }
    __syncthreads();

    uint32_t mine[4];
    uint32_t local = 0;
    for (int j = 0; j < 4; ++j) { mine[j] = hist2[t * 4 + j]; local += mine[j]; }
    ssum[t] = local;
    __syncthreads();
    for (int off = 1; off < 1024; off <<= 1) {
        uint32_t v = (t >= off) ? ssum[t - off] : 0;
        __syncthreads();
        ssum[t] += v;
        __syncthreads();
    }
    uint32_t incl = ssum[t], excl = incl - local;
    if (excl < (uint32_t)K && incl >= (uint32_t)K) {
        uint32_t run = excl;
        for (int j = 0; j < 4; ++j) {
            run += mine[j];
            if (run >= (uint32_t)K) { cut2_s = (uint32_t)(t * 4 + j); break; }
        }
    }
    __syncthreads();
    uint32_t c2 = cut2_s;

    for (int b = t; b < NBLK; b += 1024) {
        uint32_t n = gcount[b]; if (n > SLOT) n = SLOT;
        for (uint32_t j = 0; j < n; ++j) {
            unsigned long long cv = gslots[(size_t)b * SLOT + j];
            uint32_t key = (uint32_t)(cv >> 32);
            if ((uint32_t)(((unsigned long long)key * M32) >> 32) <= c2) {
                uint32_t pos = atomicAdd(&m2_s, 1u);
                if (pos < LDS_CAND) lcand[pos] = cv;
                cand2[pos] = cv;
            }
        }
    }
    for (uint32_t i = t; i < novf; i += 1024) {
        unsigned long long cv = ovf[i];
        uint32_t key = (uint32_t)(cv >> 32);
        if ((uint32_t)(((unsigned long long)key * M32) >> 32) <= c2) {
            uint32_t pos = atomicAdd(&m2_s, 1u);
            if (pos < LDS_CAND) lcand[pos] = cv;
            cand2[pos] = cv;
        }
    }
    __syncthreads();
    uint32_t M2 = m2_s;

    if (M2 <= LDS_CAND) {
        for (uint32_t i = t; i < M2; i += 1024) {
            unsigned long long ci = lcand[i];
            uint32_t rank = 0;
            for (uint32_t j = 0; j < M2; ++j) rank += (lcand[j] < ci) ? 1u : 0u;
            if (rank < (uint32_t)K) {
                uint32_t idx = (uint32_t)(ci & 0xFFFFFFFFu);
                out[3 * rank + 0] = pts[3 * idx + 0];
                out[3 * rank + 1] = pts[3 * idx + 1];
                out[3 * rank + 2] = pts[3 * idx + 2];
                out[3 * K + rank] = (float)idx;  // indices exact (< 2^23)
            }
        }
    } else {
        for (uint32_t i = t; i < M2; i += 1024) {
            unsigned long long ci = cand2[i];
            uint32_t rank = 0;
            for (uint32_t j = 0; j < M2; ++j) rank += (cand2[j] < ci) ? 1u : 0u;
            if (rank < (uint32_t)K) {
                uint32_t idx = (uint32_t)(ci & 0xFFFFFFFFu);
                out[3 * rank + 0] = pts[3 * idx + 0];
                out[3 * rank + 1] = pts[3 * idx + 1];
                out[3 * rank + 2] = pts[3 * idx + 2];
                out[3 * K + rank] = (float)idx;
            }
        }
    }
}

extern "C" void kernel_launch(void* const* d_in, const int* in_sizes, int n_in,
                              void* d_out, int out_size, void* d_ws, size_t ws_size,
                              hipStream_t stream) {
    const float* pts = (const float*)d_in[0];
    const float* P1  = (const float*)d_in[1];
    float* out = (float*)d_out;

    int N = in_sizes[0] / 3;
    int ntiles = N / TILE_PTS;
    int K = out_size / 4;  // out = K*3 coords + K indices
    int nsamp = (N < SAMP_PTS) ? (N / 4) * 4 : SAMP_PTS;

    uint32_t* w       = (uint32_t*)d_ws;
    uint32_t* ovf_cnt = w + 0;
    uint32_t* cutp    = w + 1;
    uint32_t* done_s  = w + 2;
    uint32_t* hist    = w + 4;                          // NBINS
    uint32_t* gcount  = w + 4 + NBINS;                  // NBLK
    unsigned long long* gslots = (unsigned long long*)(w + 4 + NBINS + NBLK); // NBLK*SLOT
    unsigned long long* ovf    = gslots + (size_t)NBLK * SLOT;                // OVF_CAP
    unsigned long long* cand2  = ovf + OVF_CAP;                               // LDS_CAND mirror

    // zero: ovf_cnt, cut, done_s, hist (gcount/gslots/cand2 written before read)
    hipMemsetAsync(w, 0, (size_t)(4 + NBINS) * sizeof(uint32_t), stream);
    sample_scan_kernel<<<SBLK, 256, 0, stream>>>(pts, P1, hist, cutp, done_s, nsamp, K);
    filter_kernel<<<NBLK, 256, 0, stream>>>(pts, P1, cutp, gslots, gcount,
                                            ovf_cnt, ovf, ntiles, N);
    refine_select_kernel<<<1, 1024, 0, stream>>>(gcount, gslots, ovf_cnt, ovf,
                                                 cutp, cand2, pts, out, K);
}